// Round 1
// baseline (782.598 us; speedup 1.0000x reference)
//
#include <hip/hip_runtime.h>

// FeatureOctree: out[n,:] = sum_{lvl=0..2} sum_{k=0..7} p[lvl][n][k] * feat[lvl][idx[lvl][n][k], :]
// 4 threads per point; lane `sub` in [0,4) owns float4 slice sub of the 16-dim feature.

__device__ __forceinline__ void accum_level(
    long long pt, int sub, float cx, float cy, float cz,
    const float4* __restrict__ feat, const int* __restrict__ idx,
    float4& acc)
{
    float dx = cx - floorf(cx);
    float dy = cy - floorf(cy);
    float dz = cz - floorf(cz);
    // t = 3d^2 - 2d^3
    float tx = dx * dx * (3.0f - 2.0f * dx);
    float ty = dy * dy * (3.0f - 2.0f * dy);
    float tz = dz * dz * (3.0f - 2.0f * dz);
    float ux = 1.0f - tx, uy = 1.0f - ty, uz = 1.0f - tz;

    float p[8];
    p[0] = ux * uy * uz;
    p[1] = ux * uy * tz;
    p[2] = ux * ty * uz;
    p[3] = ux * ty * tz;
    p[4] = tx * uy * uz;
    p[5] = tx * uy * tz;
    p[6] = tx * ty * uz;
    p[7] = tx * ty * tz;

    // idx row: 8 int32, 32B-aligned -> two int4 loads
    const int4* iv = (const int4*)(idx + pt * 8);
    int4 ia = iv[0];
    int4 ib = iv[1];
    int id[8] = { ia.x, ia.y, ia.z, ia.w, ib.x, ib.y, ib.z, ib.w };

#pragma unroll
    for (int k = 0; k < 8; ++k) {
        float4 g = feat[(long long)id[k] * 4 + sub];
        acc.x = fmaf(p[k], g.x, acc.x);
        acc.y = fmaf(p[k], g.y, acc.y);
        acc.z = fmaf(p[k], g.z, acc.z);
        acc.w = fmaf(p[k], g.w, acc.w);
    }
}

__global__ __launch_bounds__(256) void FeatureOctree_74749610820348_kernel(
    const float* __restrict__ x,
    const float4* __restrict__ f0,
    const float4* __restrict__ f1,
    const float4* __restrict__ f2,
    const int* __restrict__ i0,
    const int* __restrict__ i1,
    const int* __restrict__ i2,
    float4* __restrict__ out,
    int n_pts)
{
    long long tid = (long long)blockIdx.x * blockDim.x + threadIdx.x;
    long long pt = tid >> 2;
    int sub = (int)(tid & 3);
    if (pt >= n_pts) return;

    float xv = x[pt * 3 + 0];
    float yv = x[pt * 3 + 1];
    float zv = x[pt * 3 + 2];

    // base = x*0.5 + 0.5 ; coords(level) = 2^level * base
    float bx = xv * 0.5f + 0.5f;
    float by = yv * 0.5f + 0.5f;
    float bz = zv * 0.5f + 0.5f;

    float4 acc = make_float4(0.f, 0.f, 0.f, 0.f);

    accum_level(pt, sub, 4096.0f * bx, 4096.0f * by, 4096.0f * bz, f0, i0, acc); // level 12
    accum_level(pt, sub, 2048.0f * bx, 2048.0f * by, 2048.0f * bz, f1, i1, acc); // level 11
    accum_level(pt, sub, 1024.0f * bx, 1024.0f * by, 1024.0f * bz, f2, i2, acc); // level 10

    out[pt * 4 + sub] = acc;
}

extern "C" void kernel_launch(void* const* d_in, const int* in_sizes, int n_in,
                              void* d_out, int out_size, void* d_ws, size_t ws_size,
                              hipStream_t stream) {
    const float*  x  = (const float*)d_in[0];
    const float4* f0 = (const float4*)d_in[1];
    const float4* f1 = (const float4*)d_in[2];
    const float4* f2 = (const float4*)d_in[3];
    const int*    i0 = (const int*)d_in[4];
    const int*    i1 = (const int*)d_in[5];
    const int*    i2 = (const int*)d_in[6];
    float4* out = (float4*)d_out;

    int n_pts = in_sizes[0] / 3;
    long long total = (long long)n_pts * 4;
    int block = 256;
    int grid = (int)((total + block - 1) / block);

    FeatureOctree_74749610820348_kernel<<<grid, block, 0, stream>>>(
        x, f0, f1, f2, i0, i1, i2, out, n_pts);
}